// Round 10
// baseline (53.234 us; speedup 1.0000x reference)
//
#include <hip/hip_runtime.h>

namespace {
constexpr int C = 128;
constexpr int P = 32;
constexpr int HW = 256 * 256;
constexpr int B = 8;
constexpr int PXW = 64;                        // pixels per wave (4 per lane)
constexpr int BLOCK = 256;                     // 4 waves
constexpr int PIX_PER_BLK = 4 * PXW;           // 256
constexpr int BLKS_PER_IMG = HW / PIX_PER_BLK; // 256
constexpr int PREP_BLKS = 8;

typedef __attribute__((ext_vector_type(8))) short short8;
typedef __attribute__((ext_vector_type(4))) float f32x4;

__device__ inline unsigned short f2bf(float f) {
  unsigned u = __builtin_bit_cast(unsigned, f);
  return (unsigned short)((u + 0x7FFFu + ((u >> 16) & 1u)) >> 16);  // RNE
}
// one-instr packed f32->bf16 (RNE) — used on x only (proven at 2^-8 absmax)
__device__ inline unsigned pack2(float lo, float hi) {
  unsigned r;
  asm("v_cvt_pk_bf16_f32 %0, %1, %2" : "=v"(r) : "v"(lo), "v"(hi));
  return r;
}

// ws floats: [0:32) 0.5*|W_p|^2 | [32:64) alphap | [64:96) g2 | [96:128) U0 | [128:160) U1
// then ushort W_bf16[32*128] at (ws+160), row-major [p][c]
__global__ void prep_kernel(const float* __restrict__ Wp,
                            const float* __restrict__ beta,
                            const float* __restrict__ alpha,
                            const float* __restrict__ gam,
                            float* __restrict__ ws) {
  const int t = threadIdx.x;
  if (blockIdx.x == 0) {
    const int p = t >> 3, seg = t & 7;  // 8 threads per prototype
    float s = 0.f;
#pragma unroll
    for (int i = 0; i < 16; ++i) {
      const float w = Wp[p * C + seg * 16 + i];
      s = fmaf(w, w, s);
    }
#pragma unroll
    for (int m = 1; m < 8; m <<= 1) s += __shfl_xor(s, m);
    if (seg == 0) {
      ws[p] = 0.5f * s;
      ws[32 + p] = 0.99f / (1.f + __expf(-alpha[p]));
      const float gv = gam[p];
      ws[64 + p] = gv * gv;
      const float b0 = beta[p * 2 + 0], b1 = beta[p * 2 + 1];
      const float q0 = b0 * b0, q1 = b1 * b1;
      const float inv = 1.f / (q0 + q1);
      ws[96 + p] = q0 * inv;
      ws[128 + p] = q1 * inv;
    }
  }
  unsigned short* wbf = (unsigned short*)(ws + 160);
  for (int i = blockIdx.x * BLOCK + t; i < P * C; i += PREP_BLKS * BLOCK)
    wbf[i] = f2bf(Wp[i]);
}

__global__ __launch_bounds__(BLOCK, 4) void evid_kernel(
    const float* __restrict__ x, const float* __restrict__ ws,
    float* __restrict__ out) {
  const int t = threadIdx.x;
  const int blk = blockIdx.x;
  const int b = blk >> 8;  // blk / BLKS_PER_IMG
  const int px_blk = (blk & (BLKS_PER_IMG - 1)) * PIX_PER_BLK;
  const int wid = t >> 6, l = t & 63;
  const int li = l & 15;   // B column index
  const int g = l >> 4;    // k-group (0..3)
  const int px_wave = px_blk + wid * PXW;
  // lane owns pixels px_wave + 4*li + {0,1,2,3}; fragment m <-> pixel 4*li+m
  const float* __restrict__ xg = x + (size_t)b * C * HW + px_wave + 4 * li;
  const unsigned short* __restrict__ wbf = (const unsigned short*)(ws + 160);
  const int krow0 = g * 8;

  // ---- prologue: cache A-fragments (constant W_bf16) in registers ----
  short8 afr[2][4];
#pragma unroll
  for (int T = 0; T < 2; ++T)
#pragma unroll
    for (int s = 0; s < 4; ++s) {
      union { uint4 q; short8 v; } uu;
      uu.q = *reinterpret_cast<const uint4*>(wbf + (T * 16 + li) * C + s * 32 + krow0);
      afr[T][s] = uu.v;
    }

  f32x4 acc[4][2];  // [px m][proto-tile T]
#pragma unroll
  for (int m = 0; m < 4; ++m)
#pragma unroll
    for (int T = 0; T < 2; ++T) acc[m][T] = (f32x4){0.f, 0.f, 0.f, 0.f};
  float xs[4] = {0.f, 0.f, 0.f, 0.f};

#pragma unroll
  for (int s = 0; s < 4; ++s) {
    const float* xr = xg + (size_t)(s * 32 + krow0) * HW;
    f32x4 v[8];
#pragma unroll
    for (int j = 0; j < 8; ++j)
      v[j] = *reinterpret_cast<const f32x4*>(xr + (size_t)j * HW);
    union { unsigned u[4]; short8 s8; } bf[4];
#pragma unroll
    for (int m = 0; m < 4; ++m) {
      bf[m].u[0] = pack2(v[0][m], v[1][m]);
      bf[m].u[1] = pack2(v[2][m], v[3][m]);
      bf[m].u[2] = pack2(v[4][m], v[5][m]);
      bf[m].u[3] = pack2(v[6][m], v[7][m]);
    }
#pragma unroll
    for (int j = 0; j < 8; ++j)
#pragma unroll
      for (int m = 0; m < 4; ++m) xs[m] = fmaf(v[j][m], v[j][m], xs[m]);
#pragma unroll
    for (int m = 0; m < 4; ++m) {
      acc[m][0] = __builtin_amdgcn_mfma_f32_16x16x32_bf16(afr[0][s], bf[m].s8, acc[m][0], 0, 0, 0);
      acc[m][1] = __builtin_amdgcn_mfma_f32_16x16x32_bf16(afr[1][s], bf[m].s8, acc[m][1], 0, 0, 0);
    }
  }

  // full x^2 per pixel: reduce partials over the 4 k-group lanes
#pragma unroll
  for (int mask = 16; mask <= 32; mask <<= 1)
#pragma unroll
    for (int m = 0; m < 4; ++m) xs[m] += __shfl_xor(xs[m], mask);
  float x2v[4];
#pragma unroll
  for (int m = 0; m < 4; ++m) x2v[m] = 0.5f * xs[m];

  // lane-local Dempster combine over this lane's 8 prototypes, 4 pixels
  float cls0[4] = {0.f, 0.f, 0.f, 0.f};
  float cls1[4] = {0.f, 0.f, 0.f, 0.f};
  float omg[4] = {1.f, 1.f, 1.f, 1.f};
#pragma unroll
  for (int r = 0; r < 4; ++r) {
#pragma unroll
    for (int T = 0; T < 2; ++T) {
      const int p = T * 16 + g * 4 + r;
      const float w2h = ws[p];
      const float ap = ws[32 + p];
      const float g2 = ws[64 + p];
      const float U0 = ws[96 + p];
      const float U1 = ws[128 + p];
#pragma unroll
      for (int m = 0; m < 4; ++m) {
        const float d = x2v[m] + w2h - acc[m][T][r];
        const float sv = ap * __expf(-g2 * d);
        const float mO = 1.f - sv;
        const float m0 = U0 * sv, m1 = U1 * sv;
        const float n0 = fmaf(cls0[m], m0 + mO, m0 * omg[m]);
        const float n1 = fmaf(cls1[m], m1 + mO, m1 * omg[m]);
        omg[m] *= mO;
        cls0[m] = n0;
        cls1[m] = n1;
      }
    }
  }
  // merge across the 4 k-group lanes (Dempster combine is associative+commutative)
#pragma unroll
  for (int mask = 16; mask <= 32; mask <<= 1)
#pragma unroll
    for (int m = 0; m < 4; ++m) {
      const float b0 = __shfl_xor(cls0[m], mask);
      const float b1 = __shfl_xor(cls1[m], mask);
      const float bO = __shfl_xor(omg[m], mask);
      const float n0 = cls0[m] * b0 + cls0[m] * bO + omg[m] * b0;
      const float n1 = cls1[m] * b1 + cls1[m] * bO + omg[m] * b1;
      omg[m] *= bO;
      cls0[m] = n0;
      cls1[m] = n1;
    }

  if (g == 0) {
    f32x4 o0, o1, o2;
#pragma unroll
    for (int m = 0; m < 4; ++m) {
      const float inv = __builtin_amdgcn_rcpf(cls0[m] + cls1[m] + omg[m]);
      o0[m] = cls0[m] * inv;
      o1[m] = cls1[m] * inv;
      o2[m] = omg[m] * inv;
    }
    float* ob = out + (size_t)b * 3 * HW + px_wave + 4 * li;
    *reinterpret_cast<f32x4*>(ob) = o0;
    *reinterpret_cast<f32x4*>(ob + HW) = o1;
    *reinterpret_cast<f32x4*>(ob + 2 * HW) = o2;
  }
}
}  // namespace

extern "C" void kernel_launch(void* const* d_in, const int* in_sizes, int n_in,
                              void* d_out, int out_size, void* d_ws, size_t ws_size,
                              hipStream_t stream) {
  const float* feats = (const float*)d_in[0];
  const float* Wp = (const float*)d_in[1];
  const float* beta = (const float*)d_in[2];
  const float* alpha = (const float*)d_in[3];
  const float* gam = (const float*)d_in[4];
  float* ws = (float*)d_ws;
  float* out = (float*)d_out;

  hipLaunchKernelGGL(prep_kernel, dim3(PREP_BLKS), dim3(BLOCK), 0, stream, Wp,
                     beta, alpha, gam, ws);
  hipLaunchKernelGGL(evid_kernel, dim3(B * BLKS_PER_IMG), dim3(BLOCK), 0,
                     stream, feats, ws, out);
}

// Round 11
// 52.358 us; speedup vs baseline: 1.0167x; 1.0167x over previous
//
#include <hip/hip_runtime.h>

namespace {
constexpr int C = 128;
constexpr int P = 32;
constexpr int HW = 256 * 256;
constexpr int B = 8;
constexpr int PXW = 64;                        // pixels per wave (4 per lane)
constexpr int BLOCK = 256;                     // 4 waves
constexpr int PIX_PER_BLK = 4 * PXW;           // 256
constexpr int BLKS_PER_IMG = HW / PIX_PER_BLK; // 256
constexpr int PREP_BLKS = 8;

typedef __attribute__((ext_vector_type(8))) short short8;
typedef __attribute__((ext_vector_type(4))) float f32x4;

__device__ inline unsigned short f2bf(float f) {
  unsigned u = __builtin_bit_cast(unsigned, f);
  return (unsigned short)((u + 0x7FFFu + ((u >> 16) & 1u)) >> 16);  // RNE
}
// one-instr packed f32->bf16 (RNE) — used on x only (proven at 2^-8 absmax)
__device__ inline unsigned pack2(float lo, float hi) {
  unsigned r;
  asm("v_cvt_pk_bf16_f32 %0, %1, %2" : "=v"(r) : "v"(lo), "v"(hi));
  return r;
}

// ws floats: [0:32) 0.5*|W_p|^2 | [32:64) alphap | [64:96) g2 | [96:128) U0 | [128:160) U1
// then ushort W_bf16[32*128] at (ws+160), row-major [p][c]
__global__ void prep_kernel(const float* __restrict__ Wp,
                            const float* __restrict__ beta,
                            const float* __restrict__ alpha,
                            const float* __restrict__ gam,
                            float* __restrict__ ws) {
  const int t = threadIdx.x;
  if (blockIdx.x == 0) {
    const int p = t >> 3, seg = t & 7;  // 8 threads per prototype
    float s = 0.f;
#pragma unroll
    for (int i = 0; i < 16; ++i) {
      const float w = Wp[p * C + seg * 16 + i];
      s = fmaf(w, w, s);
    }
#pragma unroll
    for (int m = 1; m < 8; m <<= 1) s += __shfl_xor(s, m);
    if (seg == 0) {
      ws[p] = 0.5f * s;
      ws[32 + p] = 0.99f / (1.f + __expf(-alpha[p]));
      const float gv = gam[p];
      ws[64 + p] = gv * gv;
      const float b0 = beta[p * 2 + 0], b1 = beta[p * 2 + 1];
      const float q0 = b0 * b0, q1 = b1 * b1;
      const float inv = 1.f / (q0 + q1);
      ws[96 + p] = q0 * inv;
      ws[128 + p] = q1 * inv;
    }
  }
  unsigned short* wbf = (unsigned short*)(ws + 160);
  for (int i = blockIdx.x * BLOCK + t; i < P * C; i += PREP_BLKS * BLOCK)
    wbf[i] = f2bf(Wp[i]);
}

__global__ __launch_bounds__(BLOCK) void evid_kernel(
    const float* __restrict__ x, const float* __restrict__ ws,
    float* __restrict__ out) {
  const int t = threadIdx.x;
  const int blk = blockIdx.x;
  const int b = blk >> 8;  // blk / BLKS_PER_IMG
  const int px_blk = (blk & (BLKS_PER_IMG - 1)) * PIX_PER_BLK;
  const int wid = t >> 6, l = t & 63;
  const int li = l & 15;   // B column index
  const int g = l >> 4;    // k-group (0..3)
  const int px_wave = px_blk + wid * PXW;
  // lane owns pixels px_wave + 4*li + {0,1,2,3}; fragment m <-> pixel 4*li+m
  const float* __restrict__ xg = x + (size_t)b * C * HW + px_wave + 4 * li;
  const unsigned short* __restrict__ wbf = (const unsigned short*)(ws + 160);
  const int krow0 = g * 8;

  f32x4 acc[4][2];  // [px m][proto-tile T]
#pragma unroll
  for (int m = 0; m < 4; ++m)
#pragma unroll
    for (int T = 0; T < 2; ++T) acc[m][T] = (f32x4){0.f, 0.f, 0.f, 0.f};
  float xs[4] = {0.f, 0.f, 0.f, 0.f};

#pragma unroll
  for (int s = 0; s < 4; ++s) {
    const float* xr = xg + (size_t)(s * 32 + krow0) * HW;
    f32x4 v[8];
#pragma unroll
    for (int j = 0; j < 8; ++j)
      v[j] = *reinterpret_cast<const f32x4*>(xr + (size_t)j * HW);
    // A-fragments loaded per k-step from L1-hot W_bf16 (R9 proved caching
    // them in registers is worth zero; at 4px/lane it tips into spills)
    union { uint4 q; short8 v8; } a0, a1;
    a0.q = *reinterpret_cast<const uint4*>(wbf + li * C + s * 32 + krow0);
    a1.q = *reinterpret_cast<const uint4*>(wbf + (16 + li) * C + s * 32 + krow0);
    union { unsigned u[4]; short8 s8; } bf[4];
#pragma unroll
    for (int m = 0; m < 4; ++m) {
      bf[m].u[0] = pack2(v[0][m], v[1][m]);
      bf[m].u[1] = pack2(v[2][m], v[3][m]);
      bf[m].u[2] = pack2(v[4][m], v[5][m]);
      bf[m].u[3] = pack2(v[6][m], v[7][m]);
    }
#pragma unroll
    for (int j = 0; j < 8; ++j)
#pragma unroll
      for (int m = 0; m < 4; ++m) xs[m] = fmaf(v[j][m], v[j][m], xs[m]);
#pragma unroll
    for (int m = 0; m < 4; ++m) {
      acc[m][0] = __builtin_amdgcn_mfma_f32_16x16x32_bf16(a0.v8, bf[m].s8, acc[m][0], 0, 0, 0);
      acc[m][1] = __builtin_amdgcn_mfma_f32_16x16x32_bf16(a1.v8, bf[m].s8, acc[m][1], 0, 0, 0);
    }
  }

  // full x^2 per pixel: reduce partials over the 4 k-group lanes
#pragma unroll
  for (int mask = 16; mask <= 32; mask <<= 1)
#pragma unroll
    for (int m = 0; m < 4; ++m) xs[m] += __shfl_xor(xs[m], mask);
  float x2v[4];
#pragma unroll
  for (int m = 0; m < 4; ++m) x2v[m] = 0.5f * xs[m];

  // lane-local Dempster combine over this lane's 8 prototypes, 4 pixels
  float cls0[4] = {0.f, 0.f, 0.f, 0.f};
  float cls1[4] = {0.f, 0.f, 0.f, 0.f};
  float omg[4] = {1.f, 1.f, 1.f, 1.f};
#pragma unroll
  for (int r = 0; r < 4; ++r) {
#pragma unroll
    for (int T = 0; T < 2; ++T) {
      const int p = T * 16 + g * 4 + r;
      const float w2h = ws[p];
      const float ap = ws[32 + p];
      const float g2 = ws[64 + p];
      const float U0 = ws[96 + p];
      const float U1 = ws[128 + p];
#pragma unroll
      for (int m = 0; m < 4; ++m) {
        const float d = x2v[m] + w2h - acc[m][T][r];
        const float sv = ap * __expf(-g2 * d);
        const float mO = 1.f - sv;
        const float m0 = U0 * sv, m1 = U1 * sv;
        const float n0 = fmaf(cls0[m], m0 + mO, m0 * omg[m]);
        const float n1 = fmaf(cls1[m], m1 + mO, m1 * omg[m]);
        omg[m] *= mO;
        cls0[m] = n0;
        cls1[m] = n1;
      }
    }
  }
  // merge across the 4 k-group lanes (Dempster combine is associative+commutative)
#pragma unroll
  for (int mask = 16; mask <= 32; mask <<= 1)
#pragma unroll
    for (int m = 0; m < 4; ++m) {
      const float b0 = __shfl_xor(cls0[m], mask);
      const float b1 = __shfl_xor(cls1[m], mask);
      const float bO = __shfl_xor(omg[m], mask);
      const float n0 = cls0[m] * b0 + cls0[m] * bO + omg[m] * b0;
      const float n1 = cls1[m] * b1 + cls1[m] * bO + omg[m] * b1;
      omg[m] *= bO;
      cls0[m] = n0;
      cls1[m] = n1;
    }

  if (g == 0) {
    f32x4 o0, o1, o2;
#pragma unroll
    for (int m = 0; m < 4; ++m) {
      const float inv = __builtin_amdgcn_rcpf(cls0[m] + cls1[m] + omg[m]);
      o0[m] = cls0[m] * inv;
      o1[m] = cls1[m] * inv;
      o2[m] = omg[m] * inv;
    }
    float* ob = out + (size_t)b * 3 * HW + px_wave + 4 * li;
    *reinterpret_cast<f32x4*>(ob) = o0;
    *reinterpret_cast<f32x4*>(ob + HW) = o1;
    *reinterpret_cast<f32x4*>(ob + 2 * HW) = o2;
  }
}
}  // namespace

extern "C" void kernel_launch(void* const* d_in, const int* in_sizes, int n_in,
                              void* d_out, int out_size, void* d_ws, size_t ws_size,
                              hipStream_t stream) {
  const float* feats = (const float*)d_in[0];
  const float* Wp = (const float*)d_in[1];
  const float* beta = (const float*)d_in[2];
  const float* alpha = (const float*)d_in[3];
  const float* gam = (const float*)d_in[4];
  float* ws = (float*)d_ws;
  float* out = (float*)d_out;

  hipLaunchKernelGGL(prep_kernel, dim3(PREP_BLKS), dim3(BLOCK), 0, stream, Wp,
                     beta, alpha, gam, ws);
  hipLaunchKernelGGL(evid_kernel, dim3(B * BLKS_PER_IMG), dim3(BLOCK), 0,
                     stream, feats, ws, out);
}

// Round 12
// 47.444 us; speedup vs baseline: 1.1220x; 1.1036x over previous
//
#include <hip/hip_runtime.h>

namespace {
constexpr int C = 128;
constexpr int P = 32;
constexpr int HW = 256 * 256;
constexpr int B = 8;
constexpr int PXW = 32;                        // pixels per wave (2 per lane: even/odd)
constexpr int BLOCK = 256;                     // 4 waves
constexpr int PIX_PER_BLK = 4 * PXW;           // 128
constexpr int BLKS_PER_IMG = HW / PIX_PER_BLK; // 512
constexpr int WROW = 136;                      // LDS W row pitch in shorts (272B: 2-way-free banks)

typedef __attribute__((ext_vector_type(8))) short short8;
typedef __attribute__((ext_vector_type(4))) float f32x4;

__device__ inline unsigned short f2bf(float f) {
  unsigned u = __builtin_bit_cast(unsigned, f);
  return (unsigned short)((u + 0x7FFFu + ((u >> 16) & 1u)) >> 16);  // RNE
}
// one-instr packed f32->bf16 (RNE) — used on x only (proven at 2^-8 absmax)
__device__ inline unsigned pack2(float lo, float hi) {
  unsigned r;
  asm("v_cvt_pk_bf16_f32 %0, %1, %2" : "=v"(r) : "v"(lo), "v"(hi));
  return r;
}

__global__ __launch_bounds__(BLOCK) void evid_kernel(
    const float* __restrict__ x, const float* __restrict__ Wp,
    const float* __restrict__ beta, const float* __restrict__ alpha,
    const float* __restrict__ gam, float* __restrict__ out) {
  // tabs: [0:32) 0.5|W_p|^2 | [32:64) alphap | [64:96) g2 | [96:128) U0 | [128:160) U1
  __shared__ float tabs[160];
  __shared__ __align__(16) unsigned short wl[P * WROW];  // W bf16, padded rows

  const int t = threadIdx.x;

  // ---- per-block staging prologue (byte-identical math to the old prep) ----
  {
    const int p = t >> 3, seg = t & 7;  // 8 threads per prototype
    float s = 0.f;
#pragma unroll
    for (int i = 0; i < 16; ++i) {
      const float w = Wp[p * C + seg * 16 + i];
      s = fmaf(w, w, s);
    }
#pragma unroll
    for (int m = 1; m < 8; m <<= 1) s += __shfl_xor(s, m);
    if (seg == 0) {
      tabs[p] = 0.5f * s;
      tabs[32 + p] = 0.99f / (1.f + __expf(-alpha[p]));
      const float gv = gam[p];
      tabs[64 + p] = gv * gv;
      const float b0 = beta[p * 2 + 0], b1 = beta[p * 2 + 1];
      const float q0 = b0 * b0, q1 = b1 * b1;
      const float inv = 1.f / (q0 + q1);
      tabs[96 + p] = q0 * inv;
      tabs[128 + p] = q1 * inv;
    }
  }
  for (int i = t; i < P * C; i += BLOCK) {
    const int p = i >> 7, c = i & 127;
    wl[p * WROW + c] = f2bf(Wp[i]);
  }
  __syncthreads();

  const int blk = blockIdx.x;
  const int b = blk >> 9;  // blk / BLKS_PER_IMG
  const int px_blk = (blk & (BLKS_PER_IMG - 1)) * PIX_PER_BLK;
  const int wid = t >> 6, l = t & 63;
  const int li = l & 15;   // B column index
  const int g = l >> 4;    // k-group (0..3)
  const int px_wave = px_blk + wid * PXW;
  // lane owns pixels px_wave + 2*li (even) and +1 (odd)
  const float* __restrict__ xg = x + (size_t)b * C * HW + px_wave + 2 * li;
  const int krow0 = g * 8;

  f32x4 acc00 = {0.f, 0.f, 0.f, 0.f};  // even, proto-tile0
  f32x4 acc01 = {0.f, 0.f, 0.f, 0.f};  // even, proto-tile1
  f32x4 acc10 = {0.f, 0.f, 0.f, 0.f};  // odd,  proto-tile0
  f32x4 acc11 = {0.f, 0.f, 0.f, 0.f};  // odd,  proto-tile1
  float xs0 = 0.f, xs1 = 0.f;          // x^2 partials (even/odd)

#pragma unroll
  for (int s = 0; s < 4; ++s) {
    const float* xr = xg + (size_t)(s * 32 + krow0) * HW;
    float2 v[8];
#pragma unroll
    for (int j = 0; j < 8; ++j)
      v[j] = *reinterpret_cast<const float2*>(xr + (size_t)j * HW);
    union { uint4 q; short8 v8; } a0, a1;
    a0.q = *reinterpret_cast<const uint4*>(wl + li * WROW + s * 32 + krow0);
    a1.q = *reinterpret_cast<const uint4*>(wl + (16 + li) * WROW + s * 32 + krow0);
    union { unsigned u[4]; short8 s8; } b0, b1;
#pragma unroll
    for (int j = 0; j < 4; ++j) {
      b0.u[j] = pack2(v[2 * j].x, v[2 * j + 1].x);
      b1.u[j] = pack2(v[2 * j].y, v[2 * j + 1].y);
    }
#pragma unroll
    for (int j = 0; j < 8; ++j) {
      xs0 = fmaf(v[j].x, v[j].x, xs0);
      xs1 = fmaf(v[j].y, v[j].y, xs1);
    }
    acc00 = __builtin_amdgcn_mfma_f32_16x16x32_bf16(a0.v8, b0.s8, acc00, 0, 0, 0);
    acc01 = __builtin_amdgcn_mfma_f32_16x16x32_bf16(a1.v8, b0.s8, acc01, 0, 0, 0);
    acc10 = __builtin_amdgcn_mfma_f32_16x16x32_bf16(a0.v8, b1.s8, acc10, 0, 0, 0);
    acc11 = __builtin_amdgcn_mfma_f32_16x16x32_bf16(a1.v8, b1.s8, acc11, 0, 0, 0);
  }

  // full x^2 per pixel: reduce partials over the 4 k-group lanes
#pragma unroll
  for (int mask = 16; mask <= 32; mask <<= 1) {
    xs0 += __shfl_xor(xs0, mask);
    xs1 += __shfl_xor(xs1, mask);
  }
  const float x2v0 = 0.5f * xs0;
  const float x2v1 = 0.5f * xs1;

  // lane-local Dempster combine over this lane's 8 prototypes, both pixels
  float c00 = 0.f, c01 = 0.f, om0 = 1.f;  // even px
  float c10 = 0.f, c11 = 0.f, om1 = 1.f;  // odd px
#pragma unroll
  for (int r = 0; r < 4; ++r) {
#pragma unroll
    for (int T = 0; T < 2; ++T) {
      const int p = T * 16 + g * 4 + r;
      const float w2h = tabs[p];
      const float ap = tabs[32 + p];
      const float g2 = tabs[64 + p];
      const float U0 = tabs[96 + p];
      const float U1 = tabs[128 + p];
      const float dot0 = (T == 0) ? acc00[r] : acc01[r];
      const float dot1 = (T == 0) ? acc10[r] : acc11[r];
      {
        const float d = x2v0 + w2h - dot0;
        const float sv = ap * __expf(-g2 * d);
        const float mO = 1.f - sv;
        const float m0 = U0 * sv, m1 = U1 * sv;
        const float n0 = fmaf(c00, m0 + mO, m0 * om0);
        const float n1 = fmaf(c01, m1 + mO, m1 * om0);
        om0 *= mO;
        c00 = n0; c01 = n1;
      }
      {
        const float d = x2v1 + w2h - dot1;
        const float sv = ap * __expf(-g2 * d);
        const float mO = 1.f - sv;
        const float m0 = U0 * sv, m1 = U1 * sv;
        const float n0 = fmaf(c10, m0 + mO, m0 * om1);
        const float n1 = fmaf(c11, m1 + mO, m1 * om1);
        om1 *= mO;
        c10 = n0; c11 = n1;
      }
    }
  }
  // merge across the 4 k-group lanes (Dempster combine is associative+commutative)
#pragma unroll
  for (int mask = 16; mask <= 32; mask <<= 1) {
    {
      const float b0 = __shfl_xor(c00, mask);
      const float b1 = __shfl_xor(c01, mask);
      const float bO = __shfl_xor(om0, mask);
      const float n0 = c00 * b0 + c00 * bO + om0 * b0;
      const float n1 = c01 * b1 + c01 * bO + om0 * b1;
      om0 *= bO; c00 = n0; c01 = n1;
    }
    {
      const float b0 = __shfl_xor(c10, mask);
      const float b1 = __shfl_xor(c11, mask);
      const float bO = __shfl_xor(om1, mask);
      const float n0 = c10 * b0 + c10 * bO + om1 * b0;
      const float n1 = c11 * b1 + c11 * bO + om1 * b1;
      om1 *= bO; c10 = n0; c11 = n1;
    }
  }

  if (g == 0) {
    const float inve = __builtin_amdgcn_rcpf(c00 + c01 + om0);
    const float invo = __builtin_amdgcn_rcpf(c10 + c11 + om1);
    float* ob = out + (size_t)b * 3 * HW + px_wave + 2 * li;
    *reinterpret_cast<float2*>(ob) = make_float2(c00 * inve, c10 * invo);
    *reinterpret_cast<float2*>(ob + HW) = make_float2(c01 * inve, c11 * invo);
    *reinterpret_cast<float2*>(ob + 2 * HW) = make_float2(om0 * inve, om1 * invo);
  }
}
}  // namespace

extern "C" void kernel_launch(void* const* d_in, const int* in_sizes, int n_in,
                              void* d_out, int out_size, void* d_ws, size_t ws_size,
                              hipStream_t stream) {
  const float* feats = (const float*)d_in[0];
  const float* Wp = (const float*)d_in[1];
  const float* beta = (const float*)d_in[2];
  const float* alpha = (const float*)d_in[3];
  const float* gam = (const float*)d_in[4];
  float* out = (float*)d_out;

  hipLaunchKernelGGL(evid_kernel, dim3(B * BLKS_PER_IMG), dim3(BLOCK), 0,
                     stream, feats, Wp, beta, alpha, gam, out);
}